// Round 2
// 4471.037 us; speedup vs baseline: 1.2625x; 1.2625x over previous
//
#include <hip/hip_runtime.h>
#include <math.h>

#define NN 50000
#define EE 800000
#define RR 3
#define CHUNK 10000   // nodes per LSTM chunk (xg buffer = CHUNK*16*256 floats = 164 MB)

__device__ __forceinline__ float leaky(float x){ return x > 0.f ? x : 0.01f*x; }
__device__ __forceinline__ float sigmoid_f(float x){ return 1.f/(1.f+__expf(-x)); }
__device__ __forceinline__ float tanh_f(float x){ return 1.f - 2.f/(__expf(2.f*x)+1.f); }

// =======================================================================
// Register-tiled fp32 GEMM: D[r][wrow0+n] = act(A[r, koff:koff+K] . W[wrow0+n, :] + bias)
// BM=64 rows, BN=128 cols, BK=32. 256 threads, each owns a 4x8 C tile.
// LDS k-major (transposed on store) so inner loop = 3 ds_read_b128 per 32 FMAs.
// =======================================================================
#define GT_BM 64
#define GT_BN 128
#define GT_BK 32
#define GT_PA 68    // pitch (floats) of As  -> conflict-free reads, 16B-aligned rows
#define GT_PW 132   // pitch (floats) of Ws

__global__ __launch_bounds__(256) void gemm_tiled(
    const float* __restrict__ A, int M, int lda, int koff, int K,
    const float* __restrict__ W,            // (OUT, K) row-major
    const float* __restrict__ bias, const float* __restrict__ bias2,
    float* __restrict__ D, int ldd, int doff,
    float* __restrict__ D2, int doff2, int act)
{
  __shared__ float As[GT_BK * GT_PA];   // As[k*GT_PA + m]
  __shared__ float Ws[GT_BK * GT_PW];   // Ws[k*GT_PW + n]

  const int tid   = threadIdx.x;
  const int bm    = blockIdx.x * GT_BM;
  const int wrow0 = blockIdx.y * GT_BN;
  const int tx = tid & 15;          // n-group
  const int ty = tid >> 4;          // m-group (0..15)
  const int m0 = ty * 4;
  const int n0 = tx * 4;

  const int srow = tid >> 3;        // 0..31 staging row
  const int skq  = tid & 7;         // 0..7 staging k-quad

  float acc[4][8];
#pragma unroll
  for (int i=0;i<4;i++)
#pragma unroll
    for (int j=0;j<8;j++) acc[i][j]=0.f;

  float4 ra[2], rw[4];
  // stage-load (global -> regs) for chunk kc
  auto load_tiles = [&](int kc){
#pragma unroll
    for (int p=0;p<2;p++){
      int gr = bm + p*32 + srow; if (gr >= M) gr = M-1;
      ra[p] = *(const float4*)(A + (size_t)gr*lda + koff + kc + skq*4);
    }
#pragma unroll
    for (int p=0;p<4;p++){
      int r = p*32 + srow;        // 0..127
      rw[p] = *(const float4*)(W + (size_t)(wrow0 + r)*K + kc + skq*4);
    }
  };

  load_tiles(0);
  for (int kc = 0; kc < K; kc += GT_BK){
    if (kc) __syncthreads();
    // regs -> LDS (transposed, k-major)
#pragma unroll
    for (int p=0;p<2;p++){
      int r = p*32 + srow;
      As[(skq*4+0)*GT_PA + r] = ra[p].x;
      As[(skq*4+1)*GT_PA + r] = ra[p].y;
      As[(skq*4+2)*GT_PA + r] = ra[p].z;
      As[(skq*4+3)*GT_PA + r] = ra[p].w;
    }
#pragma unroll
    for (int p=0;p<4;p++){
      int r = p*32 + srow;
      Ws[(skq*4+0)*GT_PW + r] = rw[p].x;
      Ws[(skq*4+1)*GT_PW + r] = rw[p].y;
      Ws[(skq*4+2)*GT_PW + r] = rw[p].z;
      Ws[(skq*4+3)*GT_PW + r] = rw[p].w;
    }
    __syncthreads();
    if (kc + GT_BK < K) load_tiles(kc + GT_BK);   // overlap next-chunk HBM latency

#pragma unroll
    for (int k = 0; k < GT_BK; ++k){
      const float4 av = *(const float4*)&As[k*GT_PA + m0];
      const float4 w0 = *(const float4*)&Ws[k*GT_PW + n0];
      const float4 w1 = *(const float4*)&Ws[k*GT_PW + n0 + 64];
      const float am[4] = {av.x, av.y, av.z, av.w};
#pragma unroll
      for (int i=0;i<4;i++){
        acc[i][0] = fmaf(am[i], w0.x, acc[i][0]);
        acc[i][1] = fmaf(am[i], w0.y, acc[i][1]);
        acc[i][2] = fmaf(am[i], w0.z, acc[i][2]);
        acc[i][3] = fmaf(am[i], w0.w, acc[i][3]);
        acc[i][4] = fmaf(am[i], w1.x, acc[i][4]);
        acc[i][5] = fmaf(am[i], w1.y, acc[i][5]);
        acc[i][6] = fmaf(am[i], w1.z, acc[i][6]);
        acc[i][7] = fmaf(am[i], w1.w, acc[i][7]);
      }
    }
  }

  float4 bA = *(const float4*)(bias + wrow0 + n0);
  float4 bB = *(const float4*)(bias + wrow0 + n0 + 64);
  if (bias2){
    const float4 cA = *(const float4*)(bias2 + wrow0 + n0);
    const float4 cB = *(const float4*)(bias2 + wrow0 + n0 + 64);
    bA.x+=cA.x; bA.y+=cA.y; bA.z+=cA.z; bA.w+=cA.w;
    bB.x+=cB.x; bB.y+=cB.y; bB.z+=cB.z; bB.w+=cB.w;
  }

#pragma unroll
  for (int i=0;i<4;i++){
    const int r = bm + m0 + i;
    if (r >= M) continue;
    float4 v0 = {acc[i][0]+bA.x, acc[i][1]+bA.y, acc[i][2]+bA.z, acc[i][3]+bA.w};
    float4 v1 = {acc[i][4]+bB.x, acc[i][5]+bB.y, acc[i][6]+bB.z, acc[i][7]+bB.w};
    if (act){
      v0.x=leaky(v0.x); v0.y=leaky(v0.y); v0.z=leaky(v0.z); v0.w=leaky(v0.w);
      v1.x=leaky(v1.x); v1.y=leaky(v1.y); v1.z=leaky(v1.z); v1.w=leaky(v1.w);
    }
    *(float4*)(D + (size_t)r*ldd + doff + wrow0 + n0)      = v0;
    *(float4*)(D + (size_t)r*ldd + doff + wrow0 + n0 + 64) = v1;
    if (D2){
      *(float4*)(D2 + (size_t)r*ldd + doff2 + wrow0 + n0)      = v0;
      *(float4*)(D2 + (size_t)r*ldd + doff2 + wrow0 + n0 + 64) = v1;
    }
  }
}

// ---------------- LSTM recurrence: 128 threads, each owns gate cols (j, j+128) ----
// Doubles FMA work per LDS broadcast read vs 1-j-per-thread.
__global__ __launch_bounds__(128, 2) void lstm_rec_kernel(
    const float* __restrict__ xg,     // (chunk*16, 256)
    const float* __restrict__ Whh,    // (256, 64)
    float* __restrict__ hout)         // (chunk, 64)
{
  const int t  = threadIdx.x;         // 0..127
  const int nb = blockIdx.x * 16;
  __shared__ float hs[16*64];
  __shared__ float cs[16*64];
  __shared__ float gs[16*256];

  const int j0 = t, j1 = t + 128;
  float4 wA[16], wB[16];
#pragma unroll
  for (int i=0;i<16;i++){
    wA[i] = *(const float4*)(Whh + (size_t)j0*64 + i*4);
    wB[i] = *(const float4*)(Whh + (size_t)j1*64 + i*4);
  }

  for (int i = t; i < 16*64; i += 128){ hs[i]=0.f; cs[i]=0.f; }
  __syncthreads();

  for (int step = 0; step < 16; ++step){
    float xgA[16], xgB[16];
#pragma unroll
    for (int n=0;n<16;n++){
      const size_t base = ((size_t)(nb+n)*16 + step)*256;
      xgA[n] = xg[base + j0];
      xgB[n] = xg[base + j1];
    }

#pragma unroll 4
    for (int n = 0; n < 16; ++n){
      float4 aA = {0.f,0.f,0.f,0.f};
      float4 aB = {0.f,0.f,0.f,0.f};
#pragma unroll
      for (int kc = 0; kc < 16; ++kc){
        const float4 hv = *(const float4*)&hs[n*64 + kc*4];  // wave-uniform broadcast
        aA.x = fmaf(wA[kc].x, hv.x, aA.x);
        aA.y = fmaf(wA[kc].y, hv.y, aA.y);
        aA.z = fmaf(wA[kc].z, hv.z, aA.z);
        aA.w = fmaf(wA[kc].w, hv.w, aA.w);
        aB.x = fmaf(wB[kc].x, hv.x, aB.x);
        aB.y = fmaf(wB[kc].y, hv.y, aB.y);
        aB.z = fmaf(wB[kc].z, hv.z, aB.z);
        aB.w = fmaf(wB[kc].w, hv.w, aB.w);
      }
      gs[n*256 + j0] = (aA.x + aA.y) + (aA.z + aA.w) + xgA[n];
      gs[n*256 + j1] = (aB.x + aB.y) + (aB.z + aB.w) + xgB[n];
    }
    __syncthreads();
#pragma unroll
    for (int p = 0; p < 8; ++p){
      const int idx = p*128 + t;          // 0..1023
      const int n = idx >> 6, k = idx & 63;
      const float gi = gs[n*256 + k];
      const float gf = gs[n*256 + 64 + k];
      const float gg = gs[n*256 + 128 + k];
      const float go = gs[n*256 + 192 + k];
      float c = sigmoid_f(gf)*cs[idx] + sigmoid_f(gi)*tanh_f(gg);
      cs[idx] = c; hs[idx] = sigmoid_f(go)*tanh_f(c);
    }
    __syncthreads();
  }
#pragma unroll
  for (int p = 0; p < 2; ++p){
    const int q = p*128 + t;              // f4 id 0..255
    const int ln = q >> 4, lk = (q & 15)*4;
    *(float4*)(hout + (size_t)(nb+ln)*64 + lk) = *(float4*)&hs[ln*64 + lk];
  }
}

// ---------------- CSR build: histogram ---------------------------------------------
__global__ void hist_kernel(const int* __restrict__ dst, int* __restrict__ cnt){
  const int r = blockIdx.y;
  const int e = blockIdx.x*256 + threadIdx.x;
  if (e < EE) atomicAdd(&cnt[(size_t)r*NN + dst[(size_t)r*EE + e]], 1);
}

// dinv from int counts
__global__ void dinv_kernel(const int* __restrict__ cnt, float* __restrict__ dinv){
  int i = blockIdx.x*256 + threadIdx.x;
  if (i < RR*NN) dinv[i] = 1.f/sqrtf(fmaxf((float)cnt[i], 1.f));
}

// ---------------- CSR build: exclusive prefix sum (one block per relation) ---------
__global__ __launch_bounds__(256) void scan_kernel(
    const int* __restrict__ cnt, int* __restrict__ row_ptr)
{
  const int r = blockIdx.x;
  const int tid = threadIdx.x;
  const int* c = cnt + (size_t)r*NN;
  int* rp = row_ptr + (size_t)r*(NN+1);
  __shared__ int sdata[256];
  int running = 0;
  for (int chunk = 0; chunk < NN; chunk += 1024){
    __syncthreads();
    int idx = chunk + tid*4;
    int v0=0,v1=0,v2=0,v3=0;
    if (idx   < NN) v0 = c[idx];
    if (idx+1 < NN) v1 = c[idx+1];
    if (idx+2 < NN) v2 = c[idx+2];
    if (idx+3 < NN) v3 = c[idx+3];
    int s = v0+v1+v2+v3;
    sdata[tid] = s;
    __syncthreads();
    for (int off=1; off<256; off<<=1){
      int t = (tid >= off) ? sdata[tid-off] : 0;
      __syncthreads();
      sdata[tid] += t;
      __syncthreads();
    }
    int excl = running + sdata[tid] - s;   // exclusive prefix for this thread's 4
    if (idx   < NN) rp[idx]   = excl;
    if (idx+1 < NN) rp[idx+1] = excl + v0;
    if (idx+2 < NN) rp[idx+2] = excl + v0 + v1;
    if (idx+3 < NN) rp[idx+3] = excl + v0 + v1 + v2;
    running += sdata[255];
  }
  if (tid == 0) rp[NN] = running;   // == EE
}

// ---------------- CSR build: fill --------------------------------------------------
__global__ void fill_kernel(const int* __restrict__ src, const int* __restrict__ dst,
                            const int* __restrict__ row_ptr, int* __restrict__ cursor,
                            int* __restrict__ csr_src)
{
  const int r = blockIdx.y;
  const int e = blockIdx.x*256 + threadIdx.x;
  if (e >= EE) return;
  const int d = dst[(size_t)r*EE + e];
  const int pos = atomicAdd(&cursor[(size_t)r*NN + d], 1);
  csr_src[(size_t)r*EE + row_ptr[(size_t)r*(NN+1) + d] + pos] = src[(size_t)r*EE + e];
}

// ---------------- pull-gather + fused update: fn = f - (Σ f[s]*dinv[s]) * dinv -----
// one wave per destination node; lane = feature (64 of 128, ×2)
__global__ __launch_bounds__(256) void gather_fused(
    const int* __restrict__ csr_src, const int* __restrict__ row_ptr,
    const float* __restrict__ f, const float* __restrict__ dinv,
    float* __restrict__ fn)
{
  const int node = blockIdx.x*4 + (threadIdx.x >> 6);
  const int lane = threadIdx.x & 63;
  if (node >= NN) return;
  int p  = row_ptr[node];
  const int p1 = row_ptr[node+1];
  float a0 = 0.f, a1 = 0.f;
  for (; p + 2 <= p1; p += 2){
    const int s0 = csr_src[p];
    const int s1 = csr_src[p+1];
    const float d0 = dinv[s0];
    const float d1 = dinv[s1];
    const float f00 = f[(size_t)s0*128 + lane];
    const float f01 = f[(size_t)s0*128 + 64 + lane];
    const float f10 = f[(size_t)s1*128 + lane];
    const float f11 = f[(size_t)s1*128 + 64 + lane];
    a0 = fmaf(f00, d0, a0); a1 = fmaf(f01, d0, a1);
    a0 = fmaf(f10, d1, a0); a1 = fmaf(f11, d1, a1);
  }
  if (p < p1){
    const int s0 = csr_src[p];
    const float d0 = dinv[s0];
    a0 = fmaf(f[(size_t)s0*128 + lane], d0, a0);
    a1 = fmaf(f[(size_t)s0*128 + 64 + lane], d0, a1);
  }
  const float dvd = dinv[node];
  fn[(size_t)node*128 + lane]      = f[(size_t)node*128 + lane]      - a0*dvd;
  fn[(size_t)node*128 + 64 + lane] = f[(size_t)node*128 + 64 + lane] - a1*dvd;
}

// ---------------- attention combine + lin5 (per relation) ---------------------------
__global__ __launch_bounds__(128) void combine_kernel(
    const float* __restrict__ f0, const float* __restrict__ f1, const float* __restrict__ f2,
    const float* __restrict__ Wf1, const float* __restrict__ bf1, const float* __restrict__ Wf2,
    const float* __restrict__ W5, const float* __restrict__ b5,
    float* __restrict__ hall, int rcol)
{
  const int o = threadIdx.x;
  const int nb = blockIdx.x * 8;
  __shared__ float fs[3*8*128];
  __shared__ float red[16];

  for (int i = o; i < 768; i += 128){
    int e = i*4;
    int jj = e >> 10; int rem = e & 1023;
    int n = rem >> 7; int k = rem & 127;
    const float* fp = (jj==0) ? f0 : ((jj==1) ? f1 : f2);
    *(float4*)&fs[e] = *(const float4*)(fp + (size_t)(nb+n)*128 + k);
  }
  __syncthreads();

  float u0[8],u1[8],u2[8],w0[8],w1[8],w2[8];
#pragma unroll
  for (int n=0;n<8;n++){u0[n]=0;u1[n]=0;u2[n]=0;w0[n]=0;w1[n]=0;w2[n]=0;}

  for (int kc=0;kc<32;kc++){
    const float4 wa = *(const float4*)(Wf1 + (size_t)o*128 + kc*4);
    const float4 wb = *(const float4*)(W5  + (size_t)o*128 + kc*4);
#pragma unroll
    for (int n=0;n<8;n++){
      const float4 a0 = *(const float4*)&fs[0*1024 + n*128 + kc*4];
      const float4 a1 = *(const float4*)&fs[1*1024 + n*128 + kc*4];
      const float4 a2 = *(const float4*)&fs[2*1024 + n*128 + kc*4];
      u0[n] = fmaf(wa.x,a0.x, fmaf(wa.y,a0.y, fmaf(wa.z,a0.z, fmaf(wa.w,a0.w, u0[n]))));
      u1[n] = fmaf(wa.x,a1.x, fmaf(wa.y,a1.y, fmaf(wa.z,a1.z, fmaf(wa.w,a1.w, u1[n]))));
      u2[n] = fmaf(wa.x,a2.x, fmaf(wa.y,a2.y, fmaf(wa.z,a2.z, fmaf(wa.w,a2.w, u2[n]))));
      w0[n] = fmaf(wb.x,a0.x, fmaf(wb.y,a0.y, fmaf(wb.z,a0.z, fmaf(wb.w,a0.w, w0[n]))));
      w1[n] = fmaf(wb.x,a1.x, fmaf(wb.y,a1.y, fmaf(wb.z,a1.z, fmaf(wb.w,a1.w, w1[n]))));
      w2[n] = fmaf(wb.x,a2.x, fmaf(wb.y,a2.y, fmaf(wb.z,a2.z, fmaf(wb.w,a2.w, w2[n]))));
    }
  }

  const float bo = bf1[o], wf2o = Wf2[o], b5o = b5[o];
#pragma unroll
  for (int n=0;n<8;n++){
    float s0 = wf2o * tanh_f(fmaf( 0.8f,u0[n], fmaf(-0.5f,u1[n], bo)));
    float s1 = wf2o * tanh_f(fmaf( 3.0f,u0[n], fmaf(-3.0f,u1[n], fmaf(0.75f,u2[n], bo))));
    float s2 = wf2o * tanh_f(fmaf( 3.0f,u1[n], fmaf(-1.5f,u2[n], bo)));
    float s3 = wf2o * tanh_f(fmaf(0.75f,u2[n], bo));
    float s4 = wf2o * tanh_f(fmaf(-0.2f,u0[n], fmaf( 0.5f,u1[n], bo)));
#pragma unroll
    for (int off=32; off>0; off>>=1){
      s0 += __shfl_xor(s0, off);
      s1 += __shfl_xor(s1, off);
      s2 += __shfl_xor(s2, off);
      s3 += __shfl_xor(s3, off);
      s4 += __shfl_xor(s4, off);
    }
    if ((o & 63) == 0){
      const int w = o >> 6;
      red[w*8+0]=s0; red[w*8+1]=s1; red[w*8+2]=s2; red[w*8+3]=s3; red[w*8+4]=s4;
    }
    __syncthreads();
    float t0 = red[0]+red[8], t1 = red[1]+red[9], t2 = red[2]+red[10],
          t3 = red[3]+red[11], t4 = red[4]+red[12];
    float mx = fmaxf(fmaxf(fmaxf(t0,t1),fmaxf(t2,t3)),t4);
    float e0=__expf(t0-mx), e1=__expf(t1-mx), e2=__expf(t2-mx),
          e3=__expf(t3-mx), e4=__expf(t4-mx);
    float inv = 1.f/(e0+e1+e2+e3+e4);
    e0*=inv; e1*=inv; e2*=inv; e3*=inv; e4*=inv;
    float c0 =  0.8f*e0 + 3.0f*e1              - 0.2f*e4;
    float c1 = -0.5f*e0 - 3.0f*e1 + 3.0f*e2    + 0.5f*e4;
    float c2 =            0.75f*e1 - 1.5f*e2 + 0.75f*e3;
    float outv = fmaf(c0,w0[n], fmaf(c1,w1[n], fmaf(c2,w2[n], b5o)));
    hall[(size_t)(nb+n)*384 + rcol + o] = outv;
    __syncthreads();
  }
}

// ---------------- final: out = [act(hall), x0, x1, x2] @ W6.T + b6 ------------------
__global__ __launch_bounds__(256) void final_kernel(
    const float* __restrict__ hall, const float* __restrict__ xin,
    const float* __restrict__ W6, const float* __restrict__ b6,
    float* __restrict__ out)
{
  const int n = blockIdx.x*256 + threadIdx.x;
  if (n >= NN) return;
  float a0 = b6[0], a1 = b6[1];
  const float* h = hall + (size_t)n*384;
#pragma unroll 8
  for (int jc=0;jc<96;jc++){
    float4 v = *(const float4*)(h + jc*4);
    v.x = leaky(v.x); v.y = leaky(v.y); v.z = leaky(v.z); v.w = leaky(v.w);
    const float4 wA = *(const float4*)(W6 + jc*4);
    const float4 wB = *(const float4*)(W6 + 768 + jc*4);
    a0 = fmaf(wA.x,v.x, fmaf(wA.y,v.y, fmaf(wA.z,v.z, fmaf(wA.w,v.w, a0))));
    a1 = fmaf(wB.x,v.x, fmaf(wB.y,v.y, fmaf(wB.z,v.z, fmaf(wB.w,v.w, a1))));
  }
  for (int p=0;p<3;p++){
    const float* xp = xin + (size_t)p*NN*128 + (size_t)n*128;
    const int jb = 384 + p*128;
#pragma unroll 8
    for (int jc=0;jc<32;jc++){
      const float4 v = *(const float4*)(xp + jc*4);
      const float4 wA = *(const float4*)(W6 + jb + jc*4);
      const float4 wB = *(const float4*)(W6 + 768 + jb + jc*4);
      a0 = fmaf(wA.x,v.x, fmaf(wA.y,v.y, fmaf(wA.z,v.z, fmaf(wA.w,v.w, a0))));
      a1 = fmaf(wB.x,v.x, fmaf(wB.y,v.y, fmaf(wB.z,v.z, fmaf(wB.w,v.w, a1))));
    }
  }
  out[(size_t)n*2+0] = a0;
  out[(size_t)n*2+1] = a1;
}

extern "C" void kernel_launch(void* const* d_in, const int* in_sizes, int n_in,
                              void* d_out, int out_size, void* d_ws, size_t ws_size,
                              hipStream_t stream)
{
  (void)in_sizes; (void)n_in; (void)out_size; (void)ws_size;
  const float* voc    = (const float*)d_in[0];
  const float* sms    = (const float*)d_in[1];
  const float* pers   = (const float*)d_in[2];
  const float* Wih_v  = (const float*)d_in[3];
  const float* Whh_v  = (const float*)d_in[4];
  const float* bih_v  = (const float*)d_in[5];
  const float* bhh_v  = (const float*)d_in[6];
  const float* Wih_s  = (const float*)d_in[7];
  const float* Whh_s  = (const float*)d_in[8];
  const float* bih_s  = (const float*)d_in[9];
  const float* bhh_s  = (const float*)d_in[10];
  const float* W_lin  = (const float*)d_in[11];
  const float* b_lin  = (const float*)d_in[12];
  const float* W_lin1 = (const float*)d_in[13];
  const float* b_lin1 = (const float*)d_in[14];
  const float* W_pers = (const float*)d_in[15];
  const float* b_pers = (const float*)d_in[16];
  const float* W_lin2 = (const float*)d_in[17];
  const float* b_lin2 = (const float*)d_in[18];
  const float* W_lin3 = (const float*)d_in[19];
  const float* b_lin3 = (const float*)d_in[20];
  const float* W_lin4 = (const float*)d_in[21];
  const float* b_lin4 = (const float*)d_in[22];
  const float* W_lin5 = (const float*)d_in[23];
  const float* b_lin5 = (const float*)d_in[24];
  const float* Wf1    = (const float*)d_in[25];
  const float* bf1    = (const float*)d_in[26];
  const float* Wf2    = (const float*)d_in[27];
  const float* W_lin6 = (const float*)d_in[28];
  const float* b_lin6 = (const float*)d_in[29];
  const int*   src    = (const int*)d_in[30];
  const int*   dst    = (const int*)d_in[31];

  float* ws   = (float*)d_ws;
  float* hv   = ws;                              // N*64
  float* hs   = hv  + (size_t)NN*64;             // N*64
  float* cat  = hs  + (size_t)NN*64;             // N*512 (reused as hall N*384)
  float* xin  = cat + (size_t)NN*512;            // 3*N*128
  float* f1   = xin + (size_t)3*NN*128;          // N*128
  float* f2   = f1  + (size_t)NN*128;            // N*128
  float* dinv = f2  + (size_t)NN*128;            // 3*N floats
  int*   cnt     = (int*)(dinv + (size_t)RR*NN); // R*N
  int*   row_ptr = cnt + (size_t)RR*NN;          // R*(N+1)
  int*   cursor  = row_ptr + (size_t)RR*(NN+1);  // R*N
  int*   csr_src = cursor + (size_t)RR*NN;       // R*E
  float* hall = cat;
  float* xg   = cat;                             // LSTM-phase scratch (aliases cat+xin)
  float* out  = (float*)d_out;

  // LSTMs: per chunk, xg = input GEMM for all t (tiled GEMM), then recurrence.
  for (int ls = 0; ls < 2; ++ls){
    const float* xi  = ls ? sms   : voc;
    const float* Wih = ls ? Wih_s : Wih_v;
    const float* Whh = ls ? Whh_s : Whh_v;
    const float* bi  = ls ? bih_s : bih_v;
    const float* bh  = ls ? bhh_s : bhh_v;
    float* ho        = ls ? hs    : hv;
    for (int n0 = 0; n0 < NN; n0 += CHUNK){
      dim3 gx((CHUNK*16)/GT_BM, 2);   // 2500 x 2 (256 output cols)
      gemm_tiled<<<gx, 256, 0, stream>>>(
          xi + (size_t)n0*16*64, CHUNK*16, 64, 0, 64,
          Wih, bi, bh, xg, 256, 0, nullptr, 0, 0);
      lstm_rec_kernel<<<CHUNK/16, 128, 0, stream>>>(
          xg, Whh, ho + (size_t)n0*64);
    }
  }

  // ---- CSR build (all relations) ----
  hipMemsetAsync(cnt, 0, (size_t)RR*NN*sizeof(int), stream);
  hipMemsetAsync(cursor, 0, (size_t)RR*NN*sizeof(int), stream);
  hist_kernel<<<dim3(EE/256, RR), 256, 0, stream>>>(dst, cnt);
  dinv_kernel<<<(RR*NN+255)/256, 256, 0, stream>>>(cnt, dinv);
  scan_kernel<<<RR, 256, 0, stream>>>(cnt, row_ptr);
  fill_kernel<<<dim3(EE/256, RR), 256, 0, stream>>>(src, dst, row_ptr, cursor, csr_src);

  const int gB = (NN + GT_BM - 1) / GT_BM;   // 782

  // cat = [act(hv@Wlin+b), act(pers@Wpers+b), act(hs@Wlin1+b), act(pers@Wpers+b)]
  gemm_tiled<<<dim3(gB,1), 256, 0, stream>>>(hv,   NN, 64, 0, 64, W_lin,  b_lin,  nullptr, cat, 512,   0, nullptr, 0, 1);
  gemm_tiled<<<dim3(gB,1), 256, 0, stream>>>(hs,   NN, 64, 0, 64, W_lin1, b_lin1, nullptr, cat, 512, 256, nullptr, 0, 1);
  gemm_tiled<<<dim3(gB,1), 256, 0, stream>>>(pers, NN, 32, 0, 32, W_pers, b_pers, nullptr, cat, 512, 128, cat, 384, 1);

  // x_in
  gemm_tiled<<<dim3(gB,1), 256, 0, stream>>>(cat, NN, 512,   0, 256, W_lin2, b_lin2, nullptr, xin,                    128, 0, nullptr, 0, 1);
  gemm_tiled<<<dim3(gB,1), 256, 0, stream>>>(cat, NN, 512, 256, 256, W_lin3, b_lin3, nullptr, xin + (size_t)NN*128,   128, 0, nullptr, 0, 1);
  gemm_tiled<<<dim3(gB,1), 256, 0, stream>>>(cat, NN, 512,   0, 512, W_lin4, b_lin4, nullptr, xin + (size_t)2*NN*128, 128, 0, nullptr, 0, 1);

  for (int r = 0; r < RR; ++r){
    const float* f0 = xin + (size_t)r*NN*128;
    const float* dv = dinv + (size_t)r*NN;
    const int* cs = csr_src + (size_t)r*EE;
    const int* rp = row_ptr + (size_t)r*(NN+1);

    gather_fused<<<(NN+3)/4, 256, 0, stream>>>(cs, rp, f0, dv, f1);
    gather_fused<<<(NN+3)/4, 256, 0, stream>>>(cs, rp, f1, dv, f2);

    combine_kernel<<<NN/8, 128, 0, stream>>>(f0, f1, f2,
        Wf1 + (size_t)r*128*128, bf1 + (size_t)r*128, Wf2 + (size_t)r*128,
        W_lin5 + (size_t)r*128*128, b_lin5 + (size_t)r*128, hall, r*128);
  }

  final_kernel<<<(NN+255)/256, 256, 0, stream>>>(hall, xin, W_lin6, b_lin6, out);
}